// Round 1
// baseline (276.508 us; speedup 1.0000x reference)
//
#include <hip/hip_runtime.h>

// ---------------------------------------------------------------------------
// Fused causal MHA: LN -> QKV -> flash attention (S^T trick) -> out proj.
// bf16 MFMA path. B=4, S=2048, D=1024, H=16, hd=64.
// R12: gemm_qkv upgraded to 256x256 8-phase counted-vmcnt schedule
//      (T2 swizzle + T3/T4 deep pipeline + T5 setprio). gemm_out stays 128^2
//      (only 128 wgs at 256^2 -> half the CUs idle). attn/prep frozen.
// ---------------------------------------------------------------------------

typedef short short8 __attribute__((ext_vector_type(8)));      // 8 bf16 (A/B frag)
typedef float floatx4 __attribute__((ext_vector_type(4)));     // C/D frag
typedef unsigned short ushort4v __attribute__((ext_vector_type(4)));
typedef unsigned int uint2v __attribute__((ext_vector_type(2)));

#define MFMA16(a, b, c) __builtin_amdgcn_mfma_f32_16x16x32_bf16((a), (b), (c), 0, 0, 0)

__device__ __forceinline__ unsigned short f2bf(float f) {
  unsigned int u = __float_as_uint(f);
  u += 0x7FFFu + ((u >> 16) & 1u);
  return (unsigned short)(u >> 16);
}

#if defined(__has_builtin)
#if __has_builtin(__builtin_amdgcn_cvt_pk_bf16_f32)
#define HAVE_PK_BF16 1
#endif
#if __has_builtin(__builtin_amdgcn_exp2f)
#define EXP2(x) __builtin_amdgcn_exp2f(x)
#endif
#if __has_builtin(__builtin_amdgcn_rcpf)
#define RCP(x) __builtin_amdgcn_rcpf(x)
#endif
#endif
#ifndef EXP2
#define EXP2(x) exp2f(x)
#endif
#ifndef RCP
#define RCP(x) (1.0f / (x))
#endif

__device__ __forceinline__ unsigned int pk_bf16(float a, float b) {
#ifdef HAVE_PK_BF16
  typedef __bf16 bf16x2_t __attribute__((ext_vector_type(2)));
  union { bf16x2_t v; unsigned int u; } cvt;
  cvt.v = __builtin_amdgcn_cvt_pk_bf16_f32(a, b);
  return cvt.u;
#else
  return (unsigned int)f2bf(a) | ((unsigned int)f2bf(b) << 16);
#endif
}

// async global -> LDS, 16B per lane. LDS dest = wave-uniform base + lane*16.
__device__ __forceinline__ void async_lds16(const void* g, void* l) {
  __builtin_amdgcn_global_load_lds(
      (const __attribute__((address_space(1))) void*)g,
      (__attribute__((address_space(3))) void*)l, 16, 0, 0);
}

// ---------------------------------------------------------------------------
// Fused prep: blocks [0,1024) transpose weights fp32->bf16 into B^T layout;
// blocks [1024, 9216) do LayerNorm (one block per row).
// ---------------------------------------------------------------------------
__global__ __launch_bounds__(256) void prep_kernel(
    const float* __restrict__ wq, const float* __restrict__ wk,
    const float* __restrict__ wv, const float* __restrict__ wo,
    unsigned short* __restrict__ wqkvT, unsigned short* __restrict__ woT,
    const float* __restrict__ x, const float* __restrict__ gamma,
    const float* __restrict__ beta, unsigned short* __restrict__ h) {
  __shared__ float t[64][65];
  __shared__ float sm[4], qm[4];
  const int id = (int)blockIdx.x;
  const int tid = threadIdx.x;
  if (id < 1024) {
    const int mz = id >> 8, rem = id & 255;
    const int n0 = (rem & 15) * 64, k0 = (rem >> 4) * 64;
    const int r = tid >> 6, c = tid & 63;
    const float* src = (mz == 0) ? wq : (mz == 1) ? wk : (mz == 2) ? wv : wo;
    unsigned short* dst = (mz == 3) ? woT : (wqkvT + (size_t)mz * 1024 * 1024);
#pragma unroll
    for (int i = r; i < 64; i += 4) t[i][c] = src[(size_t)(k0 + i) * 1024 + n0 + c];
    __syncthreads();
#pragma unroll
    for (int i = r; i < 64; i += 4)
      dst[(size_t)(n0 + i) * 1024 + k0 + c] = f2bf(t[c][i]);
    return;
  }
  const int row = id - 1024;
  const float4 xv = ((const float4*)(x + (size_t)row * 1024))[tid];
  float s = xv.x + xv.y + xv.z + xv.w;
  float q = xv.x * xv.x + xv.y * xv.y + xv.z * xv.z + xv.w * xv.w;
#pragma unroll
  for (int off = 32; off > 0; off >>= 1) {
    s += __shfl_xor(s, off, 64);
    q += __shfl_xor(q, off, 64);
  }
  const int wave = tid >> 6, lane = tid & 63;
  if (lane == 0) { sm[wave] = s; qm[wave] = q; }
  __syncthreads();
  s = sm[0] + sm[1] + sm[2] + sm[3];
  q = qm[0] + qm[1] + qm[2] + qm[3];
  const float mean = s * (1.0f / 1024.0f);
  const float var = q * (1.0f / 1024.0f) - mean * mean;
  const float rstd = rsqrtf(var + 1e-5f);
  const float4 g = ((const float4*)gamma)[tid];
  const float4 bb = ((const float4*)beta)[tid];
  ushort4v o;
  o.x = f2bf((xv.x - mean) * rstd * g.x + bb.x);
  o.y = f2bf((xv.y - mean) * rstd * g.y + bb.y);
  o.z = f2bf((xv.z - mean) * rstd * g.z + bb.z);
  o.w = f2bf((xv.w - mean) * rstd * g.w + bb.w);
  ((ushort4v*)(h + (size_t)row * 1024))[tid] = o;
}

// ---------------------------------------------------------------------------
// 128x128 GEMM main loop (2-barrier structure) — retained for gemm_out only.
// ---------------------------------------------------------------------------
#define GEMM128_MAIN(A_, Bt_, m0_, n0_)                                         \
  __shared__ __align__(16) unsigned short lA[128 * 64];                         \
  __shared__ __align__(16) unsigned short lB[128 * 64];                         \
  const int tid = threadIdx.x;                                                  \
  const int wave = tid >> 6, lane = tid & 63, quad = lane >> 4, l15 = lane & 15;\
  const int wm = wave >> 1, wn = wave & 1;                                      \
  const int m0 = (m0_), n0 = (n0_);                                             \
  const int srow = tid >> 3, schunk = tid & 7;                                  \
  const int swz = l15 & 7;                                                      \
  floatx4 acc[4][4];                                                            \
  _Pragma("unroll") for (int i = 0; i < 4; i++)                                 \
  _Pragma("unroll") for (int j = 0; j < 4; j++)                                 \
      acc[i][j] = (floatx4){0.f, 0.f, 0.f, 0.f};                                \
  for (int kt = 0; kt < 16; kt++) {                                             \
    const int k0 = kt * 64;                                                     \
    __syncthreads();                                                            \
    _Pragma("unroll") for (int j = 0; j < 4; j++) {                             \
      const int row_ = j * 32 + srow;                                           \
      const int gch_ = schunk ^ (row_ & 7);                                     \
      async_lds16(A_ + (size_t)(m0 + row_) * 1024 + k0 + gch_ * 8,              \
                  (char*)lA + j * 4096 + wave * 1024);                          \
      async_lds16(Bt_ + (size_t)(n0 + row_) * 1024 + k0 + gch_ * 8,             \
                  (char*)lB + j * 4096 + wave * 1024);                          \
    }                                                                           \
    __syncthreads();                                                            \
    _Pragma("unroll") for (int kk = 0; kk < 2; kk++) {                          \
      const int ch = (kk * 4 + quad) ^ swz;                                     \
      short8 af[4], bf[4];                                                      \
      _Pragma("unroll") for (int i = 0; i < 4; i++) {                           \
        af[i] = *(const short8*)(lA + (wm * 64 + i * 16 + l15) * 64 + ch * 8);  \
        bf[i] = *(const short8*)(lB + (wn * 64 + i * 16 + l15) * 64 + ch * 8);  \
      }                                                                         \
      _Pragma("unroll") for (int mt = 0; mt < 4; mt++)                          \
      _Pragma("unroll") for (int nt = 0; nt < 4; nt++)                          \
          acc[mt][nt] = MFMA16(af[mt], bf[nt], acc[mt][nt]);                    \
    }                                                                           \
  }

// ---------------------------------------------------------------------------
// gemm_qkv: 256x256 tile, 8-phase schedule, 512 threads = 8 waves (2M x 4N).
// K = 1024 = 16 K-tiles of 64, processed 2 per iteration (dbuf parity).
// LDS 128 KB: lA/lB [buf][half][128x64] bf16, XOR-swizzled chunks.
// Per-iteration stage order: {T+1.A1 | T+2.B0 | T+2.B1 | T+2.A0 ||
//                             T+2.A1 | T+3.B0 | T+3.B1 | T+3.A0}
// A region of buf is read in phases 1-3 only (Aq0 in P1, Aq1+Aq2 in P2,
// Aq3 in P3; P4 reads nothing) -> staging A0 in P4 / A1 in P5 is
// write-after-read safe (readers' lgkmcnt(0) precedes their MFMA precedes
// barrier-2, which the stager also crossed before issuing).
// vmcnt(6) at P4/P8 = 3 half-tiles (6 loads/wave) in flight, never 0.
// ---------------------------------------------------------------------------
__global__ __launch_bounds__(512, 2) void gemm_qkv(
    const unsigned short* __restrict__ A, const unsigned short* __restrict__ Bt,
    const float* __restrict__ bq, const float* __restrict__ bk,
    const float* __restrict__ bv, unsigned short* __restrict__ qo,
    unsigned short* __restrict__ ko, unsigned short* __restrict__ vT) {
  __shared__ __align__(16) unsigned short lA[2][2][128 * 64];  // 64 KB
  __shared__ __align__(16) unsigned short lB[2][2][128 * 64];  // 64 KB
  const int tid = threadIdx.x;
  const int wave = tid >> 6, lane = tid & 63, quad = lane >> 4, l15 = lane & 15;
  const int wm = wave >> 2, wn = wave & 3;
  const int id = (int)blockIdx.x;
  // 32 M-tiles x 12 N-tiles = 384 wgs; XCD owns a 4-M-tile stripe, walks N.
  const int xcd = id & 7, rr = id >> 3;
  const int m0 = (xcd * 4 + (rr & 3)) * 256;
  const int n0 = (rr >> 2) * 256;

  // staging geometry: 512 thr x 2 loads x 16B = one 128x64 half-tile (16 KB)
  const int srow8 = tid >> 3, chunk8 = tid & 7;
  const int gch = chunk8 ^ (srow8 & 7);  // XOR swizzle (row&7 invariant in j)
  const int wave1024 = wave * 1024;
  const int swz = l15 & 7;
  const int ch0 = quad ^ swz, ch1 = (4 + quad) ^ swz;

  const unsigned short* pA0 = A + (size_t)(m0 + srow8) * 1024 + gch * 8;
  const unsigned short* pA1 = pA0 + (size_t)128 * 1024;
  const unsigned short* pB0 = Bt + (size_t)(n0 + srow8) * 1024 + gch * 8;
  const unsigned short* pB1 = pB0 + (size_t)128 * 1024;

  const unsigned short* rdA[2] = {&lA[0][wm][0] + l15 * 64,
                                  &lA[1][wm][0] + l15 * 64};
  const unsigned short* rdB[2] = {&lB[0][wn >> 1][0] + ((wn & 1) * 64 + l15) * 64,
                                  &lB[1][wn >> 1][0] + ((wn & 1) * 64 + l15) * 64};

  floatx4 acc[8][4];
#pragma unroll
  for (int i = 0; i < 8; i++)
#pragma unroll
    for (int j = 0; j < 4; j++) acc[i][j] = (floatx4){0.f, 0.f, 0.f, 0.f};

  short8 bF[4][2], aQ0[2][2], aQ1[2][2], aQ2[2][2], aQ3[2][2];

#define STG(p_, k0_, dst_)                                                     \
  {                                                                            \
    _Pragma("unroll") for (int j_ = 0; j_ < 2; j_++)                           \
        async_lds16((p_) + (size_t)j_ * 65536 + (k0_),                         \
                    (char*)(dst_) + j_ * 8192 + wave1024);                     \
  }
#define LDB(buf_)                                                              \
  _Pragma("unroll") for (int n_ = 0; n_ < 4; n_++) {                           \
    bF[n_][0] = *(const short8*)(rdB[buf_] + n_ * 1024 + ch0 * 8);             \
    bF[n_][1] = *(const short8*)(rdB[buf_] + n_ * 1024 + ch1 * 8);             \
  }
#define LDA(dst_, mb_, buf_)                                                   \
  _Pragma("unroll") for (int mm_ = 0; mm_ < 2; mm_++) {                        \
    dst_[mm_][0] = *(const short8*)(rdA[buf_] + ((mb_) + mm_) * 1024 + ch0 * 8);\
    dst_[mm_][1] = *(const short8*)(rdA[buf_] + ((mb_) + mm_) * 1024 + ch1 * 8);\
  }
#define MFQ(af_, q_)                                                           \
  __builtin_amdgcn_s_setprio(1);                                              \
  _Pragma("unroll") for (int mm_ = 0; mm_ < 2; mm_++)                          \
  _Pragma("unroll") for (int n_ = 0; n_ < 4; n_++) {                           \
    acc[(q_)*2 + mm_][n_] = MFMA16(af_[mm_][0], bF[n_][0], acc[(q_)*2 + mm_][n_]); \
    acc[(q_)*2 + mm_][n_] = MFMA16(af_[mm_][1], bF[n_][1], acc[(q_)*2 + mm_][n_]); \
  }                                                                            \
  __builtin_amdgcn_s_setprio(0);
// raw s_barrier with compiler memory fences on both sides (no vmcnt drain!)
#define BAR()                                                                  \
  {                                                                            \
    asm volatile("" ::: "memory");                                             \
    __builtin_amdgcn_s_barrier();                                              \
    asm volatile("" ::: "memory");                                             \
  }
#define WAITV(n_)                                                              \
  {                                                                            \
    asm volatile("s_waitcnt vmcnt(" #n_ ")" ::: "memory");                     \
    __builtin_amdgcn_sched_barrier(0);                                         \
  }

  // prologue: tile0 fully + tile1 {B0,B1,A0}; vmcnt(6) -> tile0 landed.
  STG(pB0, 0, &lB[0][0][0]);
  STG(pB1, 0, &lB[0][1][0]);
  STG(pA0, 0, &lA[0][0][0]);
  STG(pA1, 0, &lA[0][1][0]);
  STG(pB0, 64, &lB[1][0][0]);
  STG(pB1, 64, &lB[1][1][0]);
  STG(pA0, 64, &lA[1][0][0]);
  WAITV(6);
  BAR();

  for (int i = 0; i < 7; i++) {
    const int kA = (2 * i + 1) * 64;  // tile 2i+1
    const int kB = kA + 64;           // tile 2i+2
    const int kC = kB + 64;           // tile 2i+3
    // P1: reads B(buf0)+Aq0(buf0); stage (2i+1).A1 -> buf1
    LDB(0); LDA(aQ0, 0, 0);
    STG(pA1, kA, &lA[1][1][0]);
    BAR(); MFQ(aQ0, 0); BAR();
    // P2: reads Aq1,Aq2; stage (2i+2).B0 -> buf0 (B read only in P1)
    LDA(aQ1, 2, 0); LDA(aQ2, 4, 0);
    STG(pB0, kB, &lB[0][0][0]);
    BAR(); MFQ(aQ1, 1); BAR();
    // P3: reads Aq3; stage (2i+2).B1
    LDA(aQ3, 6, 0);
    STG(pB1, kB, &lB[0][1][0]);
    BAR(); MFQ(aQ2, 2); BAR();
    // P4: no reads; stage (2i+2).A0 (A reads done at P3); vmcnt(6) -> 2i+1 landed
    STG(pA0, kB, &lA[0][0][0]);
    WAITV(6);
    BAR(); MFQ(aQ3, 3); BAR();
    // P5: reads B(buf1)+Aq0(buf1); stage (2i+2).A1
    LDB(1); LDA(aQ0, 0, 1);
    STG(pA1, kB, &lA[0][1][0]);
    BAR(); MFQ(aQ0, 0); BAR();
    // P6: reads Aq1,Aq2; stage (2i+3).B0 -> buf1
    LDA(aQ1, 2, 1); LDA(aQ2, 4, 1);
    STG(pB0, kC, &lB[1][0][0]);
    BAR(); MFQ(aQ1, 1); BAR();
    // P7: reads Aq3; stage (2i+3).B1
    LDA(aQ3, 6, 1);
    STG(pB1, kC, &lB[1][1][0]);
    BAR(); MFQ(aQ2, 2); BAR();
    // P8: stage (2i+3).A0; vmcnt(6) -> 2i+2 landed for next iter
    STG(pA0, kC, &lA[1][0][0]);
    WAITV(6);
    BAR(); MFQ(aQ3, 3); BAR();
  }
  // epilogue iteration: tiles 14 (buf0), 15 (buf1)
  LDB(0); LDA(aQ0, 0, 0);
  STG(pA1, 15 * 64, &lA[1][1][0]);
  BAR(); MFQ(aQ0, 0); BAR();
  LDA(aQ1, 2, 0); LDA(aQ2, 4, 0);
  BAR(); MFQ(aQ1, 1); BAR();
  LDA(aQ3, 6, 0);
  BAR(); MFQ(aQ2, 2); BAR();
  WAITV(0);
  BAR(); MFQ(aQ3, 3); BAR();
  LDB(1); LDA(aQ0, 0, 1);
  MFQ(aQ0, 0);
  LDA(aQ1, 2, 1); LDA(aQ2, 4, 1);
  MFQ(aQ1, 1);
  LDA(aQ3, 6, 1);
  MFQ(aQ2, 2);
  MFQ(aQ3, 3);

  // epilogue C-write: q,k -> [b,h,s,64] (q pre-scaled); v -> [b,h,64,s]
  const int sel = n0 >> 10;  // uniform per block (256 | 1024)
  const float* bias = (sel == 0) ? bq : (sel == 1) ? bk : bv;
  const float oscale = (sel == 0) ? 0.18033688011112042f : 1.0f;  // 1/8*log2(e)
#pragma unroll
  for (int nt = 0; nt < 4; nt++) {
    const int n = n0 + wn * 64 + nt * 16 + l15;
    const int nn = n & 1023;
    const float bia = bias[nn];
    const int hidx = nn >> 6, d = nn & 63;
#pragma unroll
    for (int mt = 0; mt < 8; mt++) {
      const int mb = m0 + wm * 128 + mt * 16 + quad * 4;
      const int b = mb >> 11, sdx = mb & 2047;
      if (sel == 2) {
        ushort4v pk;
#pragma unroll
        for (int r = 0; r < 4; r++) pk[r] = f2bf(acc[mt][nt][r] + bia);
        *(ushort4v*)(vT + ((size_t)(b * 16 + hidx) * 64 + d) * 2048 + sdx) = pk;
      } else {
        unsigned short* dst =
            ((sel == 0) ? qo : ko) + ((size_t)(b * 16 + hidx) * 2048 + sdx) * 64 + d;
#pragma unroll
        for (int r = 0; r < 4; r++)
          dst[(size_t)r * 64] = f2bf((acc[mt][nt][r] + bia) * oscale);
      }
    }
  }
#undef STG
#undef LDB
#undef LDA
#undef MFQ
#undef BAR
#undef WAITV
}

// Out proj: M=8192, N=1024, fp32 output + bias. 1D grid 512, one n-tile/XCD.
__global__ __launch_bounds__(256) void gemm_out(
    const unsigned short* __restrict__ A, const unsigned short* __restrict__ Bt,
    const float* __restrict__ bo, float* __restrict__ out) {
  const int id = (int)blockIdx.x;
  GEMM128_MAIN(A, Bt, (id >> 3) * 128, (id & 7) * 128)
#pragma unroll
  for (int nt = 0; nt < 4; nt++) {
    const int n = n0 + wn * 64 + nt * 16 + l15;
    const float bia = bo[n];
#pragma unroll
    for (int mt = 0; mt < 4; mt++) {
      const int m = m0 + wm * 64 + mt * 16 + quad * 4;
#pragma unroll
      for (int r = 0; r < 4; r++) out[(size_t)(m + r) * 1024 + n] = acc[mt][nt][r] + bia;
    }
  }
}

// ---------------------------------------------------------------------------
// Flash attention, causal, S^T formulation (R10 config, frozen):
//  - native v_exp_f32 / v_rcp_f32 (no OCML expansion)
//  - V in LDS; MERGED PASSES (one sweep serves q-tiles 31-qx and qx)
//  - NO-MAX softmax (log2-domain scores), denominator via ones-MFMA
//  - XCD-locality decode; LDS 40 KB; launch_bounds(256,4).
// ---------------------------------------------------------------------------
__global__ __launch_bounds__(256, 4) void attn_kernel(
    const unsigned short* __restrict__ q, const unsigned short* __restrict__ k,
    const unsigned short* __restrict__ vT, unsigned short* __restrict__ ao) {
  __shared__ __align__(16) unsigned short lK[2][64 * 64];  // 16 KB dbuf
  __shared__ __align__(16) unsigned short lV[2][64 * 64];  // 16 KB dbuf
  __shared__ __align__(16) unsigned short lP[4][16 * 64];  // 8 KB (swizzled)
  const int tid = threadIdx.x;
  const int wave = tid >> 6, lane = tid & 63, quad = lane >> 4, l15 = lane & 15;
  const int id = (int)blockIdx.x;
  const int bh = (id & 7) * 8 + ((id >> 3) & 7);
  const int qx = id >> 6;  // 0..15
  const int b = bh >> 4, hh = bh & 15;
  const int qtA = 31 - qx, qtB = qx;  // big & small q-tiles, qtB < qtA
  const int q0wA = qtA * 64 + wave * 16, q0wB = qtB * 64 + wave * 16;
  const int ntiles = qtA + 1;

  const unsigned short* qb = q + (size_t)bh * 2048 * 64;
  const unsigned short* kb = k + (size_t)bh * 2048 * 64;
  const unsigned short* vb = vT + (size_t)bh * 64 * 2048;
  unsigned short* pw = &lP[wave][0];

  const int srow = tid >> 3, schunk = tid & 7;  // staging row / 16B chunk

  const short8 ones8 = {0x3F80, 0x3F80, 0x3F80, 0x3F80,
                        0x3F80, 0x3F80, 0x3F80, 0x3F80};

  const int sw = l15 & 7;
  const int ph0 = (0 * 4 + quad) ^ sw, ph1 = (1 * 4 + quad) ^ sw;

#define STAGE_TILE(src_, rstride_, cbase_, dst_)                                 \
  _Pragma("unroll") for (int j = 0; j < 2; j++) {                                \
    const int row_ = j * 32 + srow;                                              \
    const int gch_ = schunk ^ (row_ & 7);                                        \
    async_lds16(src_ + (size_t)row_ * (rstride_) + (cbase_) + gch_ * 8,          \
                (char*)(dst_) + j * 4096 + wave * 1024);                         \
  }

  short8 qfA[2], qfB[2];
#pragma unroll
  for (int hf = 0; hf < 2; hf++) {
    qfA[hf] = *(const short8*)(qb + (size_t)(q0wA + l15) * 64 + hf * 32 + quad * 8);
    qfB[hf] = *(const short8*)(qb + (size_t)(q0wB + l15) * 64 + hf * 32 + quad * 8);
  }

  floatx4 oA[4], oB[4];
#pragma unroll
  for (int nt = 0; nt < 4; nt++) {
    oA[nt] = (floatx4){0.f, 0.f, 0.f, 0.f};
    oB[nt] = (floatx4){0.f, 0.f, 0.f, 0.f};
  }
  floatx4 laccA = {0.f, 0.f, 0.f, 0.f}, laccB = {0.f, 0.f, 0.f, 0.f};

  STAGE_TILE(kb, 64, 0, &lK[0][0])
  STAGE_TILE(vb, 2048, 0, &lV[0][0])
  int kbase = 0;
  for (int t = 0; t < ntiles; t++, kbase += 64) {
    __syncthreads();
    if (t + 1 < ntiles) {
      const int nb = (t + 1) & 1;
      STAGE_TILE(kb, 64, (size_t)(kbase + 64) * 64, &lK[nb][0])
      STAGE_TILE(vb, 2048, (size_t)(kbase + 64), &lV[nb][0])
    }
    const unsigned short* lKc = &lK[t & 1][0];
    const unsigned short* lVc = &lV[t & 1][0];
    const bool dual = (t <= qtB);  // block-uniform

    floatx4 scA[4], scB[4];
#pragma unroll
    for (int nt = 0; nt < 4; nt++) {
      scA[nt] = (floatx4){0.f, 0.f, 0.f, 0.f};
      scB[nt] = (floatx4){0.f, 0.f, 0.f, 0.f};
      const short8 kf0 = *(const short8*)(lKc + (nt * 16 + l15) * 64 + ph0 * 8);
      const short8 kf1 = *(const short8*)(lKc + (nt * 16 + l15) * 64 + ph1 * 8);
      scA[nt] = MFMA16(kf0, qfA[0], scA[nt]);
      scA[nt] = MFMA16(kf1, qfA[1], scA[nt]);
      if (dual) {
        scB[nt] = MFMA16(kf0, qfB[0], scB[nt]);
        scB[nt] = MFMA16(kf1, qfB[1], scB[nt]);
      }
    }

    {
      const bool needmask = (kbase + 63 > q0wA);
      const int qg = q0wA + l15;
#pragma unroll
      for (int nt = 0; nt < 4; nt++) {
        float p0 = EXP2(scA[nt][0]), p1 = EXP2(scA[nt][1]);
        float p2 = EXP2(scA[nt][2]), p3 = EXP2(scA[nt][3]);
        if (needmask) {
          const int kk = kbase + nt * 16 + quad * 4;
          if (kk + 0 > qg) p0 = 0.f;
          if (kk + 1 > qg) p1 = 0.f;
          if (kk + 2 > qg) p2 = 0.f;
          if (kk + 3 > qg) p3 = 0.f;
        }
        uint2v pk2;
        pk2.x = pk_bf16(p0, p1);
        pk2.y = pk_bf16(p2, p3);
        const int phys = (nt * 2 + (quad >> 1)) ^ sw;
        *(uint2v*)(pw + l15 * 64 + phys * 8 + (quad & 1) * 4) = pk2;
      }
    }
    asm volatile("s_waitcnt lgkmcnt(0)" ::: "memory");
    short8 pfA0 = *(const short8*)(pw + l15 * 64 + ph0 * 8);
    short8 pfA1 = *(const short8*)(pw + l15 * 64 + ph1 * 8);

    short8 pfB0, pfB1;
    if (dual) {
      const bool needmask = (kbase + 63 > q0wB);
      const int qg = q0wB + l15;
#pragma unroll
      for (int nt = 0; nt < 4; nt++) {
        float p0 = EXP2(scB[nt][0]), p1 = EXP2(scB[nt][1]);
        float p2 = EXP2(scB[nt][2]), p3 = EXP2(scB[nt][3]);
        if (needmask) {
          const int kk = kbase + nt * 16 + quad * 4;
          if (kk + 0 > qg) p0 = 0.f;
          if (kk + 1 > qg) p1 = 0.f;
          if (kk + 2 > qg) p2 = 0.f;
          if (kk + 3 > qg) p3 = 0.f;
        }
        uint2v pk2;
        pk2.x = pk_bf16(p0, p1);
        pk2.y = pk_bf16(p2, p3);
        const int phys = (nt * 2 + (quad >> 1)) ^ sw;
        *(uint2v*)(pw + l15 * 64 + phys * 8 + (quad & 1) * 4) = pk2;
      }
      asm volatile("s_waitcnt lgkmcnt(0)" ::: "memory");
      pfB0 = *(const short8*)(pw + l15 * 64 + ph0 * 8);
      pfB1 = *(const short8*)(pw + l15 * 64 + ph1 * 8);
    }

#pragma unroll
    for (int hf = 0; hf < 2; hf++) {
      const short8 pfA = hf ? pfA1 : pfA0;
      laccA = MFMA16(ones8, pfA, laccA);
      if (dual) laccB = MFMA16(ones8, hf ? pfB1 : pfB0, laccB);
      const int ph = hf ? ph1 : ph0;
#pragma unroll
      for (int nt = 0; nt < 4; nt++) {
        const short8 vf = *(const short8*)(lVc + (nt * 16 + l15) * 64 + ph * 8);
        oA[nt] = MFMA16(vf, pfA, oA[nt]);
        if (dual) oB[nt] = MFMA16(vf, hf ? pfB1 : pfB0, oB[nt]);
      }
    }
  }

  {
    const float linv = RCP(laccA[0]);
    unsigned short* dst = ao + ((size_t)b * 2048 + q0wA + l15) * 1024 + hh * 64;
#pragma unroll
    for (int nt = 0; nt < 4; nt++) {
      uint2v pk2;
      pk2.x = pk_bf16(oA[nt][0] * linv, oA[nt][1] * linv);
      pk2.y = pk_bf16(oA[nt][2] * linv, oA[nt][3] * linv);
      *(uint2v*)(dst + nt * 16 + quad * 4) = pk2;
    }
  }
  {
    const float linv = RCP(laccB[0]);
    unsigned short* dst = ao + ((size_t)b * 2048 + q0wB + l15) * 1024 + hh * 64;
#pragma unroll
    for (int nt = 0; nt < 4; nt++) {
      uint2v pk2;
      pk2.x = pk_bf16(oB[nt][0] * linv, oB[nt][1] * linv);
      pk2.y = pk_bf16(oB[nt][2] * linv, oB[nt][3] * linv);
      *(uint2v*)(dst + nt * 16 + quad * 4) = pk2;
    }
  }
#undef STAGE_TILE
}

// ---------------------------------------------------------------------------
extern "C" void kernel_launch(void* const* d_in, const int* in_sizes, int n_in,
                              void* d_out, int out_size, void* d_ws, size_t ws_size,
                              hipStream_t stream) {
  const float* x = (const float*)d_in[0];
  const float* Wq = (const float*)d_in[1];
  const float* bq = (const float*)d_in[2];
  const float* Wk = (const float*)d_in[3];
  const float* bk = (const float*)d_in[4];
  const float* Wv = (const float*)d_in[5];
  const float* bv = (const float*)d_in[6];
  const float* Wo = (const float*)d_in[7];
  const float* bo = (const float*)d_in[8];
  const float* gamma = (const float*)d_in[9];
  const float* beta = (const float*)d_in[10];
  float* out = (float*)d_out;

  char* ws = (char*)d_ws;
  unsigned short* wqkvT = (unsigned short*)(ws + 0);          // 6 MB
  unsigned short* woT   = (unsigned short*)(ws + 6291456);    // 2 MB
  unsigned short* h     = (unsigned short*)(ws + 8388608);    // 16 MB
  unsigned short* qb    = (unsigned short*)(ws + 25165824);   // [b,h,s,64] 16 MB
  unsigned short* kb    = (unsigned short*)(ws + 41943040);   // [b,h,s,64] 16 MB
  unsigned short* vT    = (unsigned short*)(ws + 58720256);   // [b,h,64,s] 16 MB
  unsigned short* ao    = (unsigned short*)(ws + 75497472);   // [b,s,1024] 16 MB

  hipLaunchKernelGGL(prep_kernel, dim3(9216), dim3(256), 0, stream,
                     Wq, Wk, Wv, Wo, wqkvT, woT, x, gamma, beta, h);
  hipLaunchKernelGGL(gemm_qkv, dim3(384), dim3(512), 0, stream,
                     h, wqkvT, bq, bk, bv, qb, kb, vT);
  hipLaunchKernelGGL(attn_kernel, dim3(1024), dim3(256), 0, stream, qb, kb, vT, ao);
  hipLaunchKernelGGL(gemm_out, dim3(512), dim3(256), 0, stream, ao, woT, bo, out);
}

// Round 2
// 262.111 us; speedup vs baseline: 1.0549x; 1.0549x over previous
//
#include <hip/hip_runtime.h>

// ---------------------------------------------------------------------------
// Fused causal MHA: LN -> QKV -> flash attention (S^T trick) -> out proj.
// bf16 MFMA path. B=4, S=2048, D=1024, H=16, hd=64.
// R13: gemm_qkv reverted to proven 128^2 2-barrier structure (R12's 8-phase
//      port was stall-bound at 542 TF). NEW: LDS-bounce coalesced epilogue
//      (FETCH/WRITE showed 2x RMW amplification from sub-line stores).
//      attn: + s_setprio around MFMA clusters (T5, m191: +4-7% on attn).
// ---------------------------------------------------------------------------

typedef short short8 __attribute__((ext_vector_type(8)));      // 8 bf16 (A/B frag)
typedef float floatx4 __attribute__((ext_vector_type(4)));     // C/D frag
typedef unsigned short ushort4v __attribute__((ext_vector_type(4)));
typedef unsigned int uint2v __attribute__((ext_vector_type(2)));

#define MFMA16(a, b, c) __builtin_amdgcn_mfma_f32_16x16x32_bf16((a), (b), (c), 0, 0, 0)

__device__ __forceinline__ unsigned short f2bf(float f) {
  unsigned int u = __float_as_uint(f);
  u += 0x7FFFu + ((u >> 16) & 1u);
  return (unsigned short)(u >> 16);
}

#if defined(__has_builtin)
#if __has_builtin(__builtin_amdgcn_cvt_pk_bf16_f32)
#define HAVE_PK_BF16 1
#endif
#if __has_builtin(__builtin_amdgcn_exp2f)
#define EXP2(x) __builtin_amdgcn_exp2f(x)
#endif
#if __has_builtin(__builtin_amdgcn_rcpf)
#define RCP(x) __builtin_amdgcn_rcpf(x)
#endif
#endif
#ifndef EXP2
#define EXP2(x) exp2f(x)
#endif
#ifndef RCP
#define RCP(x) (1.0f / (x))
#endif

__device__ __forceinline__ unsigned int pk_bf16(float a, float b) {
#ifdef HAVE_PK_BF16
  typedef __bf16 bf16x2_t __attribute__((ext_vector_type(2)));
  union { bf16x2_t v; unsigned int u; } cvt;
  cvt.v = __builtin_amdgcn_cvt_pk_bf16_f32(a, b);
  return cvt.u;
#else
  return (unsigned int)f2bf(a) | ((unsigned int)f2bf(b) << 16);
#endif
}

// async global -> LDS, 16B per lane. LDS dest = wave-uniform base + lane*16.
__device__ __forceinline__ void async_lds16(const void* g, void* l) {
  __builtin_amdgcn_global_load_lds(
      (const __attribute__((address_space(1))) void*)g,
      (__attribute__((address_space(3))) void*)l, 16, 0, 0);
}

// ---------------------------------------------------------------------------
// Fused prep: blocks [0,1024) transpose weights fp32->bf16 into B^T layout;
// blocks [1024, 9216) do LayerNorm (one block per row).
// ---------------------------------------------------------------------------
__global__ __launch_bounds__(256) void prep_kernel(
    const float* __restrict__ wq, const float* __restrict__ wk,
    const float* __restrict__ wv, const float* __restrict__ wo,
    unsigned short* __restrict__ wqkvT, unsigned short* __restrict__ woT,
    const float* __restrict__ x, const float* __restrict__ gamma,
    const float* __restrict__ beta, unsigned short* __restrict__ h) {
  __shared__ float t[64][65];
  __shared__ float sm[4], qm[4];
  const int id = (int)blockIdx.x;
  const int tid = threadIdx.x;
  if (id < 1024) {
    const int mz = id >> 8, rem = id & 255;
    const int n0 = (rem & 15) * 64, k0 = (rem >> 4) * 64;
    const int r = tid >> 6, c = tid & 63;
    const float* src = (mz == 0) ? wq : (mz == 1) ? wk : (mz == 2) ? wv : wo;
    unsigned short* dst = (mz == 3) ? woT : (wqkvT + (size_t)mz * 1024 * 1024);
#pragma unroll
    for (int i = r; i < 64; i += 4) t[i][c] = src[(size_t)(k0 + i) * 1024 + n0 + c];
    __syncthreads();
#pragma unroll
    for (int i = r; i < 64; i += 4)
      dst[(size_t)(n0 + i) * 1024 + k0 + c] = f2bf(t[c][i]);
    return;
  }
  const int row = id - 1024;
  const float4 xv = ((const float4*)(x + (size_t)row * 1024))[tid];
  float s = xv.x + xv.y + xv.z + xv.w;
  float q = xv.x * xv.x + xv.y * xv.y + xv.z * xv.z + xv.w * xv.w;
#pragma unroll
  for (int off = 32; off > 0; off >>= 1) {
    s += __shfl_xor(s, off, 64);
    q += __shfl_xor(q, off, 64);
  }
  const int wave = tid >> 6, lane = tid & 63;
  if (lane == 0) { sm[wave] = s; qm[wave] = q; }
  __syncthreads();
  s = sm[0] + sm[1] + sm[2] + sm[3];
  q = qm[0] + qm[1] + qm[2] + qm[3];
  const float mean = s * (1.0f / 1024.0f);
  const float var = q * (1.0f / 1024.0f) - mean * mean;
  const float rstd = rsqrtf(var + 1e-5f);
  const float4 g = ((const float4*)gamma)[tid];
  const float4 bb = ((const float4*)beta)[tid];
  ushort4v o;
  o.x = f2bf((xv.x - mean) * rstd * g.x + bb.x);
  o.y = f2bf((xv.y - mean) * rstd * g.y + bb.y);
  o.z = f2bf((xv.z - mean) * rstd * g.z + bb.z);
  o.w = f2bf((xv.w - mean) * rstd * g.w + bb.w);
  ((ushort4v*)(h + (size_t)row * 1024))[tid] = o;
}

// ---------------------------------------------------------------------------
// 128x128 GEMM main loop: BK=64 (16 barrier-pairs x 32 MFMA) with
// XOR-swizzled LDS (global chunk ^ (row&7)) -> conflict-free ds_read_b128.
// LDS 32 KB (one lAB[2][...] region so epilogues can reuse all 32 KB).
// ---------------------------------------------------------------------------
#define GEMM128_MAIN(A_, Bt_, m0_, n0_)                                         \
  __shared__ __align__(16) unsigned short lAB[2][128 * 64];                     \
  unsigned short* const lA = &lAB[0][0];                                        \
  unsigned short* const lB = &lAB[1][0];                                        \
  const int tid = threadIdx.x;                                                  \
  const int wave = tid >> 6, lane = tid & 63, quad = lane >> 4, l15 = lane & 15;\
  const int wm = wave >> 1, wn = wave & 1;                                      \
  const int m0 = (m0_), n0 = (n0_);                                             \
  const int srow = tid >> 3, schunk = tid & 7;                                  \
  const int swz = l15 & 7;                                                      \
  floatx4 acc[4][4];                                                            \
  _Pragma("unroll") for (int i = 0; i < 4; i++)                                 \
  _Pragma("unroll") for (int j = 0; j < 4; j++)                                 \
      acc[i][j] = (floatx4){0.f, 0.f, 0.f, 0.f};                                \
  for (int kt = 0; kt < 16; kt++) {                                             \
    const int k0 = kt * 64;                                                     \
    __syncthreads();                                                            \
    _Pragma("unroll") for (int j = 0; j < 4; j++) {                             \
      const int row_ = j * 32 + srow;                                           \
      const int gch_ = schunk ^ (row_ & 7);                                     \
      async_lds16(A_ + (size_t)(m0 + row_) * 1024 + k0 + gch_ * 8,              \
                  (char*)lA + j * 4096 + wave * 1024);                          \
      async_lds16(Bt_ + (size_t)(n0 + row_) * 1024 + k0 + gch_ * 8,             \
                  (char*)lB + j * 4096 + wave * 1024);                          \
    }                                                                           \
    __syncthreads();                                                            \
    _Pragma("unroll") for (int kk = 0; kk < 2; kk++) {                          \
      const int ch = (kk * 4 + quad) ^ swz;                                     \
      short8 af[4], bf[4];                                                      \
      _Pragma("unroll") for (int i = 0; i < 4; i++) {                           \
        af[i] = *(const short8*)(lA + (wm * 64 + i * 16 + l15) * 64 + ch * 8);  \
        bf[i] = *(const short8*)(lB + (wn * 64 + i * 16 + l15) * 64 + ch * 8);  \
      }                                                                         \
      _Pragma("unroll") for (int mt = 0; mt < 4; mt++)                          \
      _Pragma("unroll") for (int nt = 0; nt < 4; nt++)                          \
          acc[mt][nt] = MFMA16(af[mt], bf[nt], acc[mt][nt]);                    \
    }                                                                           \
  }

// QKV: M=8192, N=3072. q,k -> [b,h,s,64]; v -> [b,h,64,s].
// q PRE-SCALED by 0.125*log2(e). 1D grid 1536, XCD n-stripe swizzle.
// LDS-bounce epilogue: stage C-tile into the (now dead) 32 KB lAB region with
// XOR-swizzled chunks, then fully-coalesced 16B/lane global stores.
__global__ __launch_bounds__(256) void gemm_qkv(
    const unsigned short* __restrict__ A, const unsigned short* __restrict__ Bt,
    const float* __restrict__ bq, const float* __restrict__ bk,
    const float* __restrict__ bv, unsigned short* __restrict__ qo,
    unsigned short* __restrict__ ko, unsigned short* __restrict__ vT) {
  const int id = (int)blockIdx.x;
  const int xcd = id & 7, rr = id >> 3;
  GEMM128_MAIN(A, Bt, (rr / 3) * 128, (xcd * 3 + (rr % 3)) * 128)
  const int sel = n0 >> 10;  // uniform per block
  const float* bias = (sel == 0) ? bq : (sel == 1) ? bk : bv;
  const float oscale = (sel == 0) ? 0.18033688011112042f : 1.0f;  // 1/8 * log2(e)
  unsigned short* const st = &lAB[0][0];  // 128x128 ushort = 32 KB staging
  const int b16 = (m0 >> 11) * 16;        // batch*16 (block within one batch)
  const int h0 = (n0 & 1023) >> 6;        // first head covered by this n-tile
  const int ms = m0 & 2047;               // token offset within batch
  __syncthreads();                        // all MFMA LDS reads done
  if (sel == 2) {
    // ---- v: stage [n][m] (rows = d, cols = s), 8B vector writes.
    // chunk(8B) swizzle: phys = chunk ^ ((n&15)<<1) (even XOR -> 16B reads
    // stay contiguous, slot16 = j ^ (n&15), no half-swap needed).
#pragma unroll
    for (int nt = 0; nt < 4; nt++) {
      const int nl = wn * 64 + nt * 16 + l15;
      const float bia = bias[(n0 + nl) & 1023];
      const int x = (nl & 15) << 1;
#pragma unroll
      for (int mt = 0; mt < 4; mt++) {
        const int chunk = wm * 16 + mt * 4 + quad;  // 8B chunk along m
        ushort4v pk;
#pragma unroll
        for (int r = 0; r < 4; r++) pk[r] = f2bf(acc[mt][nt][r] + bia);
        *(ushort4v*)((char*)st + nl * 256 + ((chunk ^ x) << 3)) = pk;
      }
    }
    __syncthreads();
#pragma unroll
    for (int p = 0; p < 8; p++) {
      const int nl = p * 16 + (tid >> 4);
      const int j2 = tid & 15;
      const short8 vv =
          *(const short8*)((char*)st + nl * 256 + ((j2 ^ (nl & 15)) << 4));
      *(short8*)(vT + ((size_t)(b16 + h0 + (nl >> 6)) * 64 + (nl & 63)) * 2048 +
                 ms + j2 * 8) = vv;
    }
  } else {
    // ---- q/k: stage [m][n] (rows = s, cols = d), scalar 2B writes.
    // chunk(16B) swizzle: phys = chunk ^ (m&7).
#pragma unroll
    for (int nt = 0; nt < 4; nt++) {
      const int nl = wn * 64 + nt * 16 + l15;
      const float bia = bias[(n0 + nl) & 1023];
      const int chunk = nl >> 3, nin = nl & 7;
#pragma unroll
      for (int mt = 0; mt < 4; mt++) {
#pragma unroll
        for (int r = 0; r < 4; r++) {
          const int ml = wm * 64 + mt * 16 + quad * 4 + r;
          *(unsigned short*)((char*)st + ml * 256 + ((chunk ^ (ml & 7)) << 4) +
                             nin * 2) = f2bf((acc[mt][nt][r] + bia) * oscale);
        }
      }
    }
    __syncthreads();
    unsigned short* const dq = (sel == 0) ? qo : ko;
#pragma unroll
    for (int p = 0; p < 8; p++) {
      const int ml = p * 16 + (tid >> 4);
      const int j = tid & 15;
      const short8 vv =
          *(const short8*)((char*)st + ml * 256 + ((j ^ (ml & 7)) << 4));
      *(short8*)(dq + ((size_t)(b16 + h0 + (j >> 3)) * 2048 + (ms + ml)) * 64 +
                 (j & 7) * 8) = vv;
    }
  }
}

// Out proj: M=8192, N=1024, fp32 output + bias. 1D grid 512, one n-tile/XCD.
// (fp32 16-lane rows are already full 64B lines -> no bounce needed.)
__global__ __launch_bounds__(256) void gemm_out(
    const unsigned short* __restrict__ A, const unsigned short* __restrict__ Bt,
    const float* __restrict__ bo, float* __restrict__ out) {
  const int id = (int)blockIdx.x;
  GEMM128_MAIN(A, Bt, (id >> 3) * 128, (id & 7) * 128)
#pragma unroll
  for (int nt = 0; nt < 4; nt++) {
    const int n = n0 + wn * 64 + nt * 16 + l15;
    const float bia = bo[n];
#pragma unroll
    for (int mt = 0; mt < 4; mt++) {
      const int m = m0 + wm * 64 + mt * 16 + quad * 4;
#pragma unroll
      for (int r = 0; r < 4; r++) out[(size_t)(m + r) * 1024 + n] = acc[mt][nt][r] + bia;
    }
  }
}

// ---------------------------------------------------------------------------
// Flash attention, causal, S^T formulation (R10 config + T5 setprio):
//  - native v_exp_f32 / v_rcp_f32 (no OCML expansion)
//  - V in LDS; MERGED PASSES (one sweep serves q-tiles 31-qx and qx)
//  - NO-MAX softmax (log2-domain scores), denominator via ones-MFMA
//  - XCD-locality decode; LDS 40 KB; launch_bounds(256,4)
//  - s_setprio(1) around QK^T and PV MFMA clusters (independent blocks at
//    different phases share each CU -> T5 mechanism applies, m191 +4-7%).
// ---------------------------------------------------------------------------
__global__ __launch_bounds__(256, 4) void attn_kernel(
    const unsigned short* __restrict__ q, const unsigned short* __restrict__ k,
    const unsigned short* __restrict__ vT, unsigned short* __restrict__ ao) {
  __shared__ __align__(16) unsigned short lK[2][64 * 64];  // 16 KB dbuf
  __shared__ __align__(16) unsigned short lV[2][64 * 64];  // 16 KB dbuf
  __shared__ __align__(16) unsigned short lP[4][16 * 64];  // 8 KB (swizzled)
  const int tid = threadIdx.x;
  const int wave = tid >> 6, lane = tid & 63, quad = lane >> 4, l15 = lane & 15;
  const int id = (int)blockIdx.x;
  const int bh = (id & 7) * 8 + ((id >> 3) & 7);
  const int qx = id >> 6;  // 0..15
  const int b = bh >> 4, hh = bh & 15;
  const int qtA = 31 - qx, qtB = qx;  // big & small q-tiles, qtB < qtA
  const int q0wA = qtA * 64 + wave * 16, q0wB = qtB * 64 + wave * 16;
  const int ntiles = qtA + 1;

  const unsigned short* qb = q + (size_t)bh * 2048 * 64;
  const unsigned short* kb = k + (size_t)bh * 2048 * 64;
  const unsigned short* vb = vT + (size_t)bh * 64 * 2048;
  unsigned short* pw = &lP[wave][0];

  const int srow = tid >> 3, schunk = tid & 7;  // staging row / 16B chunk

  const short8 ones8 = {0x3F80, 0x3F80, 0x3F80, 0x3F80,
                        0x3F80, 0x3F80, 0x3F80, 0x3F80};

  const int sw = l15 & 7;
  const int ph0 = (0 * 4 + quad) ^ sw, ph1 = (1 * 4 + quad) ^ sw;

#define STAGE_TILE(src_, rstride_, cbase_, dst_)                                 \
  _Pragma("unroll") for (int j = 0; j < 2; j++) {                                \
    const int row_ = j * 32 + srow;                                              \
    const int gch_ = schunk ^ (row_ & 7);                                        \
    async_lds16(src_ + (size_t)row_ * (rstride_) + (cbase_) + gch_ * 8,          \
                (char*)(dst_) + j * 4096 + wave * 1024);                         \
  }

  short8 qfA[2], qfB[2];
#pragma unroll
  for (int hf = 0; hf < 2; hf++) {
    qfA[hf] = *(const short8*)(qb + (size_t)(q0wA + l15) * 64 + hf * 32 + quad * 8);
    qfB[hf] = *(const short8*)(qb + (size_t)(q0wB + l15) * 64 + hf * 32 + quad * 8);
  }

  floatx4 oA[4], oB[4];
#pragma unroll
  for (int nt = 0; nt < 4; nt++) {
    oA[nt] = (floatx4){0.f, 0.f, 0.f, 0.f};
    oB[nt] = (floatx4){0.f, 0.f, 0.f, 0.f};
  }
  floatx4 laccA = {0.f, 0.f, 0.f, 0.f}, laccB = {0.f, 0.f, 0.f, 0.f};

  STAGE_TILE(kb, 64, 0, &lK[0][0])
  STAGE_TILE(vb, 2048, 0, &lV[0][0])
  int kbase = 0;
  for (int t = 0; t < ntiles; t++, kbase += 64) {
    __syncthreads();
    if (t + 1 < ntiles) {
      const int nb = (t + 1) & 1;
      STAGE_TILE(kb, 64, (size_t)(kbase + 64) * 64, &lK[nb][0])
      STAGE_TILE(vb, 2048, (size_t)(kbase + 64), &lV[nb][0])
    }
    const unsigned short* lKc = &lK[t & 1][0];
    const unsigned short* lVc = &lV[t & 1][0];
    const bool dual = (t <= qtB);  // block-uniform

    floatx4 scA[4], scB[4];
    __builtin_amdgcn_s_setprio(1);
#pragma unroll
    for (int nt = 0; nt < 4; nt++) {
      scA[nt] = (floatx4){0.f, 0.f, 0.f, 0.f};
      scB[nt] = (floatx4){0.f, 0.f, 0.f, 0.f};
      const short8 kf0 = *(const short8*)(lKc + (nt * 16 + l15) * 64 + ph0 * 8);
      const short8 kf1 = *(const short8*)(lKc + (nt * 16 + l15) * 64 + ph1 * 8);
      scA[nt] = MFMA16(kf0, qfA[0], scA[nt]);
      scA[nt] = MFMA16(kf1, qfA[1], scA[nt]);
      if (dual) {
        scB[nt] = MFMA16(kf0, qfB[0], scB[nt]);
        scB[nt] = MFMA16(kf1, qfB[1], scB[nt]);
      }
    }
    __builtin_amdgcn_s_setprio(0);

    {
      const bool needmask = (kbase + 63 > q0wA);
      const int qg = q0wA + l15;
#pragma unroll
      for (int nt = 0; nt < 4; nt++) {
        float p0 = EXP2(scA[nt][0]), p1 = EXP2(scA[nt][1]);
        float p2 = EXP2(scA[nt][2]), p3 = EXP2(scA[nt][3]);
        if (needmask) {
          const int kk = kbase + nt * 16 + quad * 4;
          if (kk + 0 > qg) p0 = 0.f;
          if (kk + 1 > qg) p1 = 0.f;
          if (kk + 2 > qg) p2 = 0.f;
          if (kk + 3 > qg) p3 = 0.f;
        }
        uint2v pk2;
        pk2.x = pk_bf16(p0, p1);
        pk2.y = pk_bf16(p2, p3);
        const int phys = (nt * 2 + (quad >> 1)) ^ sw;
        *(uint2v*)(pw + l15 * 64 + phys * 8 + (quad & 1) * 4) = pk2;
      }
    }
    asm volatile("s_waitcnt lgkmcnt(0)" ::: "memory");
    short8 pfA0 = *(const short8*)(pw + l15 * 64 + ph0 * 8);
    short8 pfA1 = *(const short8*)(pw + l15 * 64 + ph1 * 8);

    short8 pfB0, pfB1;
    if (dual) {
      const bool needmask = (kbase + 63 > q0wB);
      const int qg = q0wB + l15;
#pragma unroll
      for (int nt = 0; nt < 4; nt++) {
        float p0 = EXP2(scB[nt][0]), p1 = EXP2(scB[nt][1]);
        float p2 = EXP2(scB[nt][2]), p3 = EXP2(scB[nt][3]);
        if (needmask) {
          const int kk = kbase + nt * 16 + quad * 4;
          if (kk + 0 > qg) p0 = 0.f;
          if (kk + 1 > qg) p1 = 0.f;
          if (kk + 2 > qg) p2 = 0.f;
          if (kk + 3 > qg) p3 = 0.f;
        }
        uint2v pk2;
        pk2.x = pk_bf16(p0, p1);
        pk2.y = pk_bf16(p2, p3);
        const int phys = (nt * 2 + (quad >> 1)) ^ sw;
        *(uint2v*)(pw + l15 * 64 + phys * 8 + (quad & 1) * 4) = pk2;
      }
      asm volatile("s_waitcnt lgkmcnt(0)" ::: "memory");
      pfB0 = *(const short8*)(pw + l15 * 64 + ph0 * 8);
      pfB1 = *(const short8*)(pw + l15 * 64 + ph1 * 8);
    }

    __builtin_amdgcn_s_setprio(1);
#pragma unroll
    for (int hf = 0; hf < 2; hf++) {
      const short8 pfA = hf ? pfA1 : pfA0;
      laccA = MFMA16(ones8, pfA, laccA);
      if (dual) laccB = MFMA16(ones8, hf ? pfB1 : pfB0, laccB);
      const int ph = hf ? ph1 : ph0;
#pragma unroll
      for (int nt = 0; nt < 4; nt++) {
        const short8 vf = *(const short8*)(lVc + (nt * 16 + l15) * 64 + ph * 8);
        oA[nt] = MFMA16(vf, pfA, oA[nt]);
        if (dual) oB[nt] = MFMA16(vf, hf ? pfB1 : pfB0, oB[nt]);
      }
    }
    __builtin_amdgcn_s_setprio(0);
  }

  {
    const float linv = RCP(laccA[0]);
    unsigned short* dst = ao + ((size_t)b * 2048 + q0wA + l15) * 1024 + hh * 64;
#pragma unroll
    for (int nt = 0; nt < 4; nt++) {
      uint2v pk2;
      pk2.x = pk_bf16(oA[nt][0] * linv, oA[nt][1] * linv);
      pk2.y = pk_bf16(oA[nt][2] * linv, oA[nt][3] * linv);
      *(uint2v*)(dst + nt * 16 + quad * 4) = pk2;
    }
  }
  {
    const float linv = RCP(laccB[0]);
    unsigned short* dst = ao + ((size_t)b * 2048 + q0wB + l15) * 1024 + hh * 64;
#pragma unroll
    for (int nt = 0; nt < 4; nt++) {
      uint2v pk2;
      pk2.x = pk_bf16(oB[nt][0] * linv, oB[nt][1] * linv);
      pk2.y = pk_bf16(oB[nt][2] * linv, oB[nt][3] * linv);
      *(uint2v*)(dst + nt * 16 + quad * 4) = pk2;
    }
  }
#undef STAGE_TILE
}

// ---------------------------------------------------------------------------
extern "C" void kernel_launch(void* const* d_in, const int* in_sizes, int n_in,
                              void* d_out, int out_size, void* d_ws, size_t ws_size,
                              hipStream_t stream) {
  const float* x = (const float*)d_in[0];
  const float* Wq = (const float*)d_in[1];
  const float* bq = (const float*)d_in[2];
  const float* Wk = (const float*)d_in[3];
  const float* bk = (const float*)d_in[4];
  const float* Wv = (const float*)d_in[5];
  const float* bv = (const float*)d_in[6];
  const float* Wo = (const float*)d_in[7];
  const float* bo = (const float*)d_in[8];
  const float* gamma = (const float*)d_in[9];
  const float* beta = (const float*)d_in[10];
  float* out = (float*)d_out;

  char* ws = (char*)d_ws;
  unsigned short* wqkvT = (unsigned short*)(ws + 0);          // 6 MB
  unsigned short* woT   = (unsigned short*)(ws + 6291456);    // 2 MB
  unsigned short* h     = (unsigned short*)(ws + 8388608);    // 16 MB
  unsigned short* qb    = (unsigned short*)(ws + 25165824);   // [b,h,s,64] 16 MB
  unsigned short* kb    = (unsigned short*)(ws + 41943040);   // [b,h,s,64] 16 MB
  unsigned short* vT    = (unsigned short*)(ws + 58720256);   // [b,h,64,s] 16 MB
  unsigned short* ao    = (unsigned short*)(ws + 75497472);   // [b,s,1024] 16 MB

  hipLaunchKernelGGL(prep_kernel, dim3(9216), dim3(256), 0, stream,
                     Wq, Wk, Wv, Wo, wqkvT, woT, x, gamma, beta, h);
  hipLaunchKernelGGL(gemm_qkv, dim3(1536), dim3(256), 0, stream,
                     h, wqkvT, bq, bk, bv, qb, kb, vT);
  hipLaunchKernelGGL(attn_kernel, dim3(1024), dim3(256), 0, stream, qb, kb, vT, ao);
  hipLaunchKernelGGL(gemm_out, dim3(512), dim3(256), 0, stream, ao, woT, bo, out);
}